// Round 7
// baseline (1067.966 us; speedup 1.0000x reference)
//
#include <hip/hip_runtime.h>

#pragma clang fp contract(off)

#define CDIM 256
#define N_TOKS 8192
#define N_CODES 8192

// token index -> padded LDS offset: groups of 8 tokens at stride 12 floats
// (48B) so per-wave ds_read_b128 addresses spread 2-way (free) instead of
// 4-way at 32B stride. Keeps 16B alignment (12 % 4 == 0).
#define ZMAP(x) ((x) + (((x) >> 3) << 2))

// ---------------- ws layout (bytes) ----------------
// 0       pairs   u64[8192*8]   512KB
// 524288  A       f32[8192]     32KB
// 557056  fidx    u32[8192]     32KB
// 589824  counts  u32[8192]     32KB
// 622592  bsum    f32[8]        32B

__device__ __forceinline__ unsigned enc_f(float f) {
    unsigned u = __float_as_uint(f);
    return (u & 0x80000000u) ? ~u : (u | 0x80000000u);
}

// ---------------- A_n = np.sum(zf*zf, axis=1), numpy pairwise order ----------
__global__ void vq_A_kernel(const float* __restrict__ z, float* __restrict__ A) {
    #pragma clang fp contract(off)
    const int n = blockIdx.x * blockDim.x + threadIdx.x;
    const int b = n >> 10, hw = n & 1023;
    const float* zp = z + (size_t)b * (CDIM * 1024) + hw;
    float halves[2];
    #pragma unroll
    for (int h = 0; h < 2; ++h) {
        const int base = h * 128;
        float r[8];
        #pragma unroll
        for (int j = 0; j < 8; ++j) {
            const float v = zp[(size_t)(base + j) * 1024];
            r[j] = v * v;
        }
        for (int i = 8; i < 128; i += 8) {
            #pragma unroll
            for (int j = 0; j < 8; ++j) {
                const float v = zp[(size_t)(base + i + j) * 1024];
                const float x = v * v;
                r[j] = r[j] + x;
            }
        }
        halves[h] = ((r[0] + r[1]) + (r[2] + r[3])) + ((r[4] + r[5]) + (r[6] + r[7]));
    }
    A[n] = halves[0] + halves[1];
}

// ---------------- main argmin: d_k = fl(A - 2*G_k), np.einsum SSE order ------
// G_k = (l0+l1)+(l2+l3); lane j = sequential unfused sum over channels == j mod 4.
// 512 threads: 16 token-groups (8 tok) x 32 code-groups (2 codes).
// Per block: 128 tokens x 1024 codes in 16 ct-steps of 64 codes.
// acc[4][8][2] = 64 live accumulators -> fits the 128-VGPR budget with NO
// spills (R3/R5/R6 all spilled 122MB with acc[4][8][4]=128 accs; the
// allocator refuses to exceed 128 VGPRs regardless of occupancy hints).
// 66KB LDS -> 2 blocks/CU = 4 waves/EU, consistent with the 128-VGPR cap.
__global__ __launch_bounds__(512)
void vq_argmin_kernel(
        const float* __restrict__ z, const float* __restrict__ emb,
        const float* __restrict__ A, unsigned long long* __restrict__ pairs) {
    #pragma clang fp contract(off)
    __shared__ float zs[64][192];   // [channel][ZMAP(token)]  48KB
    __shared__ float es[64][72];    // [channel][code]         18KB
    unsigned long long (*red)[32] = (unsigned long long (*)[32])&zs[0][0];  // 32KB alias

    const int t  = threadIdx.x;
    const int tg = t & 15;          // token group: tokens tg*8 .. tg*8+7
    const int cg = t >> 4;          // code group (0..31): codes cg*2, cg*2+1
    const int tg8 = tg * 8;
    const int tgp = ZMAP(tg8);      // = tg * 12
    const int cg2 = cg * 2;
    const int tile_t0 = blockIdx.x * 128;
    const int b   = tile_t0 >> 10;
    const int hw0 = tile_t0 & 1023;
    const int ks  = blockIdx.y * 1024;
    const float* zb = z + (size_t)b * (CDIM * 1024) + hw0;

    float Ar[8];
    #pragma unroll
    for (int i = 0; i < 8; ++i) Ar[i] = A[tile_t0 + tg8 + i];

    unsigned long long best[8];
    #pragma unroll
    for (int i = 0; i < 8; ++i) best[i] = ~0ull;

    for (int ct = 0; ct < 16; ++ct) {
        const int k0 = ks + ct * 64;
        float acc[4][8][2];
        #pragma unroll
        for (int j = 0; j < 4; ++j)
            #pragma unroll
            for (int i = 0; i < 8; ++i) {
                acc[j][i][0] = 0.0f;
                acc[j][i][1] = 0.0f;
            }

        for (int cc = 0; cc < 4; ++cc) {
            const int cbase = cc * 64;
            __syncthreads();
            // ---- stage zs[c][tok]: 64 ch x 128 tok, coalesced float4 ----
            {
                const int j4 = (t & 31) * 4;
                const int jp = ZMAP(j4);
                const int c0 = t >> 5;          // 0..15
                #pragma unroll
                for (int i = 0; i < 4; ++i) {
                    const int c = c0 + i * 16;
                    float4 v = *(const float4*)(zb + (size_t)(cbase + c) * 1024 + j4);
                    *(float4*)&zs[c][jp] = v;
                }
            }
            // ---- stage es[c][code]: 64 ch x 64 codes ----
            {
                const int k  = t & 63;
                const int cq = t >> 6;          // 0..7 -> channels cq*8..+7
                const float* er = emb + (size_t)(k0 + k) * CDIM + cbase + cq * 8;
                #pragma unroll
                for (int h = 0; h < 2; ++h) {
                    float4 v = *(const float4*)(er + h * 4);
                    es[cq * 8 + h * 4 + 0][k] = v.x;
                    es[cq * 8 + h * 4 + 1][k] = v.y;
                    es[cq * 8 + h * 4 + 2][k] = v.z;
                    es[cq * 8 + h * 4 + 3][k] = v.w;
                }
            }
            __syncthreads();
            // ---- unfused 4-lane accumulation (np.einsum SSE order) ----
            #pragma unroll 2
            for (int m = 0; m < 16; ++m) {
                #pragma unroll
                for (int j = 0; j < 4; ++j) {
                    const int c = m * 4 + j;    // lane j: channels == j mod 4, ascending
                    const float4 za = *(const float4*)&zs[c][tgp];
                    const float4 zc = *(const float4*)&zs[c][tgp + 4];
                    const float2 ev = *(const float2*)&es[c][cg2];
                    const float zr[8] = {za.x, za.y, za.z, za.w, zc.x, zc.y, zc.z, zc.w};
                    #pragma unroll
                    for (int i = 0; i < 8; ++i) {
                        const float p0 = zr[i] * ev.x;       // rne product
                        acc[j][i][0] = acc[j][i][0] + p0;    // rne add (no FMA)
                        const float p1 = zr[i] * ev.y;
                        acc[j][i][1] = acc[j][i][1] + p1;
                    }
                }
            }
        }
        // ---- fold: G = (l0+l1)+(l2+l3); d = fl(A - 2G); first-index min ----
        #pragma unroll
        for (int i = 0; i < 8; ++i) {
            #pragma unroll
            for (int jj = 0; jj < 2; ++jj) {
                const float g = (acc[0][i][jj] + acc[1][i][jj])
                              + (acc[2][i][jj] + acc[3][i][jj]);
                const float d = Ar[i] - 2.0f * g;
                const unsigned long long key =
                    ((unsigned long long)enc_f(d) << 32) | (unsigned)(k0 + cg2 + jj);
                if (key < best[i]) best[i] = key;
            }
        }
    }

    // ---- block reduce across the 32 code-groups per token ----
    __syncthreads();
    #pragma unroll
    for (int i = 0; i < 8; ++i) red[tg8 + i][cg] = best[i];
    __syncthreads();
    if (t < 128) {
        unsigned long long m = red[t][0];
        #pragma unroll
        for (int q = 1; q < 32; ++q) {
            const unsigned long long r = red[t][q];
            m = (r < m) ? r : m;
        }
        pairs[(size_t)(tile_t0 + t) * 8 + blockIdx.y] = m;
    }
}

// ---------------- merge splits -> fidx, out2, counts ----------------
__global__ void vq_combine_kernel(const unsigned long long* __restrict__ pairs,
                                  float* __restrict__ out2, unsigned* __restrict__ fidx,
                                  unsigned* __restrict__ counts) {
    const int n = blockIdx.x * blockDim.x + threadIdx.x;
    unsigned long long bk = pairs[(size_t)n * 8];
    #pragma unroll
    for (int s = 1; s < 8; ++s) {
        const unsigned long long k = pairs[(size_t)n * 8 + s];
        bk = (k < bk) ? k : bk;
    }
    const unsigned idx = (unsigned)(bk & 0xFFFFFFFFull);
    fidx[n] = idx;
    out2[n] = (float)idx;
    atomicAdd(&counts[idx], 1u);
}

// ---------------- gather z_q, ST-exact out0, per-batch MSE ----------------
__global__ void vq_gather_kernel(const unsigned* __restrict__ fidx,
                                 const float* __restrict__ emb,
                                 const float* __restrict__ z,
                                 float* __restrict__ out0, float* __restrict__ bsum) {
    #pragma clang fp contract(off)
    __shared__ float tile[64][257];
    const int t    = threadIdx.x;
    const int tok0 = blockIdx.x * 64;
    const int b    = tok0 >> 10;
    const int hw0  = tok0 & 1023;

    const int tt = t >> 2;
    const int q  = t & 3;
    const int idx = (int)fidx[tok0 + tt];
    const float* er = emb + (size_t)idx * CDIM;
    #pragma unroll
    for (int i = 0; i < 16; ++i) {
        const int f = i * 4 + q;
        float4 v = *(const float4*)(er + f * 4);
        tile[tt][f * 4 + 0] = v.x;
        tile[tt][f * 4 + 1] = v.y;
        tile[tt][f * 4 + 2] = v.z;
        tile[tt][f * 4 + 3] = v.w;
    }
    __syncthreads();

    const int j  = t & 63;
    const int c0 = t >> 6;
    const size_t base = (size_t)b * (CDIM * 1024) + hw0 + j;
    float s = 0.0f;
    #pragma unroll 4
    for (int c = c0; c < CDIM; c += 4) {
        const float v  = tile[j][c];
        const float zv = z[base + (size_t)c * 1024];
        const float d  = v - zv;                  // fl(z_q - z)
        out0[base + (size_t)c * 1024] = zv + d;   // straight-through
        s += d * d;
    }
    #pragma unroll
    for (int o = 32; o > 0; o >>= 1) s += __shfl_down(s, o, 64);
    __shared__ float w4[4];
    if ((t & 63) == 0) w4[t >> 6] = s;
    __syncthreads();
    if (t == 0) atomicAdd(&bsum[b], w4[0] + w4[1] + w4[2] + w4[3]);
}

// ---------------- finalize ----------------
__global__ void vq_final_kernel(const unsigned* __restrict__ counts,
                                const float* __restrict__ bsum,
                                float* __restrict__ out1, float* __restrict__ out3,
                                float* __restrict__ out4, float* __restrict__ out5) {
    const int t = threadIdx.x;
    float s = 0.0f;
    for (int k = t; k < N_CODES; k += 256) {
        const float p = (float)counts[k] * (1.0f / 8192.0f);
        s += p * logf(p + 1e-10f);
    }
    #pragma unroll
    for (int o = 32; o > 0; o >>= 1) s += __shfl_down(s, o, 64);
    __shared__ float w4[4];
    if ((t & 63) == 0) w4[t >> 6] = s;
    __syncthreads();
    if (t == 0) {
        out5[0] = expf(-(w4[0] + w4[1] + w4[2] + w4[3]));
        float tot = 0.0f;
        #pragma unroll
        for (int b = 0; b < 8; ++b) {
            const float m = bsum[b] * (1.0f / 262144.0f);
            out1[b] = 1.25f * m;
            tot += m;
        }
        const float mean_mse = tot * 0.125f;
        out3[0] = mean_mse;
        out4[0] = 0.25f * mean_mse;
    }
}

extern "C" void kernel_launch(void* const* d_in, const int* in_sizes, int n_in,
                              void* d_out, int out_size, void* d_ws, size_t ws_size,
                              hipStream_t stream) {
    const float* z   = (const float*)d_in[0];
    const float* emb = (const float*)d_in[1];
    float* out = (float*)d_out;

    float* out0 = out;                 // z_q_st (NCHW), 2097152
    float* out1 = out + 2097152;       // loss [8]
    float* out2 = out + 2097160;       // idx as float [8192]
    float* out3 = out + 2105352;       // mean commit
    float* out4 = out + 2105353;       // beta * mean emb
    float* out5 = out + 2105354;       // perplexity

    char* ws = (char*)d_ws;
    unsigned long long* pairs = (unsigned long long*)(ws + 0);
    float*    A      = (float*)(ws + 524288);
    unsigned* fidx   = (unsigned*)(ws + 557056);
    unsigned* counts = (unsigned*)(ws + 589824);
    float*    bsum   = (float*)(ws + 622592);

    hipMemsetAsync(ws + 589824, 0, 32768 + 32, stream);  // counts + bsum

    vq_A_kernel<<<N_TOKS / 256, 256, 0, stream>>>(z, A);
    vq_argmin_kernel<<<dim3(64, 8), 512, 0, stream>>>(z, emb, A, pairs);
    vq_combine_kernel<<<N_TOKS / 256, 256, 0, stream>>>(pairs, out2, fidx, counts);
    vq_gather_kernel<<<N_TOKS / 64, 256, 0, stream>>>(fidx, emb, z, out0, bsum);
    vq_final_kernel<<<1, 256, 0, stream>>>(counts, bsum, out1, out3, out4, out5);
}

// Round 8
// 984.073 us; speedup vs baseline: 1.0853x; 1.0853x over previous
//
#include <hip/hip_runtime.h>

#pragma clang fp contract(off)

#define CDIM 256
#define N_TOKS 8192
#define N_CODES 8192

// token index -> padded LDS offset: groups of 8 tokens at stride 12 floats
// (48B) so per-wave ds_read_b128 addresses spread 2-way (free) instead of
// 4-way at 32B stride. Keeps 16B alignment (12 % 4 == 0).
#define ZMAP(x) ((x) + (((x) >> 3) << 2))

// ---------------- ws layout (bytes) ----------------
// 0       pairs   u64[8192*8]   512KB
// 524288  A       f32[8192]     32KB
// 557056  fidx    u32[8192]     32KB
// 589824  counts  u32[8192]     32KB
// 622592  bsum    f32[8]        32B

__device__ __forceinline__ unsigned enc_f(float f) {
    unsigned u = __float_as_uint(f);
    return (u & 0x80000000u) ? ~u : (u | 0x80000000u);
}

// ---------------- A_n = np.sum(zf*zf, axis=1), numpy pairwise order ----------
__global__ void vq_A_kernel(const float* __restrict__ z, float* __restrict__ A) {
    #pragma clang fp contract(off)
    const int n = blockIdx.x * blockDim.x + threadIdx.x;
    const int b = n >> 10, hw = n & 1023;
    const float* zp = z + (size_t)b * (CDIM * 1024) + hw;
    float halves[2];
    #pragma unroll
    for (int h = 0; h < 2; ++h) {
        const int base = h * 128;
        float r[8];
        #pragma unroll
        for (int j = 0; j < 8; ++j) {
            const float v = zp[(size_t)(base + j) * 1024];
            r[j] = v * v;
        }
        for (int i = 8; i < 128; i += 8) {
            #pragma unroll
            for (int j = 0; j < 8; ++j) {
                const float v = zp[(size_t)(base + i + j) * 1024];
                const float x = v * v;
                r[j] = r[j] + x;
            }
        }
        halves[h] = ((r[0] + r[1]) + (r[2] + r[3])) + ((r[4] + r[5]) + (r[6] + r[7]));
    }
    A[n] = halves[0] + halves[1];
}

// ---------------- main argmin: d_k = fl(A - 2*G_k), np.einsum SSE order ------
// Residue-split across waves: j = t>>7 (channels == j mod 4, 2 waves per class).
// Each thread: 8 tok x 8 codes tile, 64 accumulators (lane-j partial only).
// T=C=8 satisfies T*C > 3(T+C): 4 b128 LDS reads per 128 MAC ops -> VALU-bound
// (R7 at C=2 was LDS-issue-bound: 3 reads per 32 MACs).
// Fold G=(l0+l1)+(l2+l3) per ct-step via LDS chunks (bit-exact numpy order).
__global__ __launch_bounds__(512)
void vq_argmin_kernel(
        const float* __restrict__ z, const float* __restrict__ emb,
        const float* __restrict__ A, unsigned long long* __restrict__ pairs) {
    #pragma clang fp contract(off)
    __shared__ float zs[64][192];   // [channel][ZMAP(token)]  49KB
    __shared__ float es[64][72];    // [channel][code]         18KB
    float (*fb)[516] = (float (*)[516])&zs[0][0];                        // 33KB alias
    unsigned long long (*red)[8] = (unsigned long long (*)[8])&es[0][0]; // 8KB alias

    const int t  = threadIdx.x;
    const int j  = t >> 7;          // residue class: channels == j (mod 4)
    const int u  = t & 127;
    const int tg = u & 15;          // token group: tokens tg*8 .. tg*8+7
    const int cg = u >> 4;          // code group (0..7): codes cg*8 .. cg*8+7
    const int tg8 = tg * 8;
    const int tgp = ZMAP(tg8);      // = tg*12
    const int cg8 = cg * 8;
    const int tile_t0 = blockIdx.x * 128;
    const int b   = tile_t0 >> 10;
    const int hw0 = tile_t0 & 1023;
    const int ks  = blockIdx.y * 1024;
    const float* zb = z + (size_t)b * (CDIM * 1024) + hw0;

    float Ar[8];
    #pragma unroll
    for (int i = 0; i < 8; ++i) Ar[i] = A[tile_t0 + tg8 + i];

    unsigned long long best[8];
    #pragma unroll
    for (int i = 0; i < 8; ++i) best[i] = ~0ull;

    for (int ct = 0; ct < 16; ++ct) {
        const int k0 = ks + ct * 64;
        float acc[8][8];
        #pragma unroll
        for (int i = 0; i < 8; ++i)
            #pragma unroll
            for (int jj = 0; jj < 8; ++jj) acc[i][jj] = 0.0f;

        for (int cc = 0; cc < 4; ++cc) {
            const int cbase = cc * 64;
            __syncthreads();
            // ---- stage zs[c][tok]: 64 ch x 128 tok, coalesced float4 ----
            {
                const int j4 = (t & 31) * 4;
                const int jp = ZMAP(j4);
                const int c0 = t >> 5;          // 0..15
                #pragma unroll
                for (int i2 = 0; i2 < 4; ++i2) {
                    const int c = c0 + i2 * 16;
                    float4 v = *(const float4*)(zb + (size_t)(cbase + c) * 1024 + j4);
                    *(float4*)&zs[c][jp] = v;
                }
            }
            // ---- stage es[c][code]: 64 ch x 64 codes ----
            {
                const int k  = t & 63;
                const int cq = t >> 6;          // 0..7 -> channels cq*8..+7
                const float* er = emb + (size_t)(k0 + k) * CDIM + cbase + cq * 8;
                #pragma unroll
                for (int h = 0; h < 2; ++h) {
                    float4 v = *(const float4*)(er + h * 4);
                    es[cq * 8 + h * 4 + 0][k] = v.x;
                    es[cq * 8 + h * 4 + 1][k] = v.y;
                    es[cq * 8 + h * 4 + 2][k] = v.z;
                    es[cq * 8 + h * 4 + 3][k] = v.w;
                }
            }
            __syncthreads();
            // ---- lane-j partial: channels lc = 4m+j ascending, unfused ----
            #pragma unroll 2
            for (int m = 0; m < 16; ++m) {
                const int lc = 4 * m + j;       // wave-uniform row
                const float4 za = *(const float4*)&zs[lc][tgp];
                const float4 zc = *(const float4*)&zs[lc][tgp + 4];
                const float4 ea = *(const float4*)&es[lc][cg8];
                const float4 eb = *(const float4*)&es[lc][cg8 + 4];
                const float zr[8]  = {za.x, za.y, za.z, za.w, zc.x, zc.y, zc.z, zc.w};
                const float er8[8] = {ea.x, ea.y, ea.z, ea.w, eb.x, eb.y, eb.z, eb.w};
                #pragma unroll
                for (int i = 0; i < 8; ++i)
                    #pragma unroll
                    for (int jj = 0; jj < 8; ++jj) {
                        const float p = zr[i] * er8[jj];   // rne product
                        acc[i][jj] = acc[i][jj] + p;       // rne add (no FMA)
                    }
            }
        }
        // ---- cross-wave fold: G = (l0+l1)+(l2+l3), exact numpy order ----
        __syncthreads();   // zs reads done before fb overwrite
        #pragma unroll
        for (int q = 0; q < 4; ++q) {          // fully unrolled: static acc idx
            #pragma unroll
            for (int i = 0; i < 8; ++i) {
                fb[i * 2 + 0][t] = acc[i][q * 2 + 0];
                fb[i * 2 + 1][t] = acc[i][q * 2 + 1];
            }
            __syncthreads();
            if (j == 0) {
                #pragma unroll
                for (int i = 0; i < 8; ++i)
                    #pragma unroll
                    for (int r = 0; r < 2; ++r) {
                        const int f = i * 2 + r;
                        const float l1 = fb[f][128 + u];
                        const float l2 = fb[f][256 + u];
                        const float l3 = fb[f][384 + u];
                        const float g  = (acc[i][q * 2 + r] + l1) + (l2 + l3);
                        const float d  = Ar[i] - 2.0f * g;
                        const unsigned long long key =
                            ((unsigned long long)enc_f(d) << 32)
                            | (unsigned)(k0 + cg8 + q * 2 + r);
                        if (key < best[i]) best[i] = key;
                    }
            }
            __syncthreads();
        }
    }

    // ---- block reduce across the 8 code-groups per token ----
    __syncthreads();
    if (j == 0) {
        #pragma unroll
        for (int i = 0; i < 8; ++i) red[tg8 + i][cg] = best[i];
    }
    __syncthreads();
    if (t < 128) {
        unsigned long long m = red[t][0];
        #pragma unroll
        for (int q = 1; q < 8; ++q) {
            const unsigned long long r = red[t][q];
            m = (r < m) ? r : m;
        }
        pairs[(size_t)(tile_t0 + t) * 8 + blockIdx.y] = m;
    }
}

// ---------------- merge splits -> fidx, out2, counts ----------------
__global__ void vq_combine_kernel(const unsigned long long* __restrict__ pairs,
                                  float* __restrict__ out2, unsigned* __restrict__ fidx,
                                  unsigned* __restrict__ counts) {
    const int n = blockIdx.x * blockDim.x + threadIdx.x;
    unsigned long long bk = pairs[(size_t)n * 8];
    #pragma unroll
    for (int s = 1; s < 8; ++s) {
        const unsigned long long k = pairs[(size_t)n * 8 + s];
        bk = (k < bk) ? k : bk;
    }
    const unsigned idx = (unsigned)(bk & 0xFFFFFFFFull);
    fidx[n] = idx;
    out2[n] = (float)idx;
    atomicAdd(&counts[idx], 1u);
}

// ---------------- gather z_q, ST-exact out0, per-batch MSE ----------------
__global__ void vq_gather_kernel(const unsigned* __restrict__ fidx,
                                 const float* __restrict__ emb,
                                 const float* __restrict__ z,
                                 float* __restrict__ out0, float* __restrict__ bsum) {
    #pragma clang fp contract(off)
    __shared__ float tile[64][257];
    const int t    = threadIdx.x;
    const int tok0 = blockIdx.x * 64;
    const int b    = tok0 >> 10;
    const int hw0  = tok0 & 1023;

    const int tt = t >> 2;
    const int q  = t & 3;
    const int idx = (int)fidx[tok0 + tt];
    const float* er = emb + (size_t)idx * CDIM;
    #pragma unroll
    for (int i = 0; i < 16; ++i) {
        const int f = i * 4 + q;
        float4 v = *(const float4*)(er + f * 4);
        tile[tt][f * 4 + 0] = v.x;
        tile[tt][f * 4 + 1] = v.y;
        tile[tt][f * 4 + 2] = v.z;
        tile[tt][f * 4 + 3] = v.w;
    }
    __syncthreads();

    const int jj = t & 63;
    const int c0 = t >> 6;
    const size_t base = (size_t)b * (CDIM * 1024) + hw0 + jj;
    float s = 0.0f;
    #pragma unroll 4
    for (int c = c0; c < CDIM; c += 4) {
        const float v  = tile[jj][c];
        const float zv = z[base + (size_t)c * 1024];
        const float d  = v - zv;                  // fl(z_q - z)
        out0[base + (size_t)c * 1024] = zv + d;   // straight-through
        s += d * d;
    }
    #pragma unroll
    for (int o = 32; o > 0; o >>= 1) s += __shfl_down(s, o, 64);
    __shared__ float w4[4];
    if ((t & 63) == 0) w4[t >> 6] = s;
    __syncthreads();
    if (t == 0) atomicAdd(&bsum[b], w4[0] + w4[1] + w4[2] + w4[3]);
}

// ---------------- finalize ----------------
__global__ void vq_final_kernel(const unsigned* __restrict__ counts,
                                const float* __restrict__ bsum,
                                float* __restrict__ out1, float* __restrict__ out3,
                                float* __restrict__ out4, float* __restrict__ out5) {
    const int t = threadIdx.x;
    float s = 0.0f;
    for (int k = t; k < N_CODES; k += 256) {
        const float p = (float)counts[k] * (1.0f / 8192.0f);
        s += p * logf(p + 1e-10f);
    }
    #pragma unroll
    for (int o = 32; o > 0; o >>= 1) s += __shfl_down(s, o, 64);
    __shared__ float w4[4];
    if ((t & 63) == 0) w4[t >> 6] = s;
    __syncthreads();
    if (t == 0) {
        out5[0] = expf(-(w4[0] + w4[1] + w4[2] + w4[3]));
        float tot = 0.0f;
        #pragma unroll
        for (int b = 0; b < 8; ++b) {
            const float m = bsum[b] * (1.0f / 262144.0f);
            out1[b] = 1.25f * m;
            tot += m;
        }
        const float mean_mse = tot * 0.125f;
        out3[0] = mean_mse;
        out4[0] = 0.25f * mean_mse;
    }
}

extern "C" void kernel_launch(void* const* d_in, const int* in_sizes, int n_in,
                              void* d_out, int out_size, void* d_ws, size_t ws_size,
                              hipStream_t stream) {
    const float* z   = (const float*)d_in[0];
    const float* emb = (const float*)d_in[1];
    float* out = (float*)d_out;

    float* out0 = out;                 // z_q_st (NCHW), 2097152
    float* out1 = out + 2097152;       // loss [8]
    float* out2 = out + 2097160;       // idx as float [8192]
    float* out3 = out + 2105352;       // mean commit
    float* out4 = out + 2105353;       // beta * mean emb
    float* out5 = out + 2105354;       // perplexity

    char* ws = (char*)d_ws;
    unsigned long long* pairs = (unsigned long long*)(ws + 0);
    float*    A      = (float*)(ws + 524288);
    unsigned* fidx   = (unsigned*)(ws + 557056);
    unsigned* counts = (unsigned*)(ws + 589824);
    float*    bsum   = (float*)(ws + 622592);

    hipMemsetAsync(ws + 589824, 0, 32768 + 32, stream);  // counts + bsum

    vq_A_kernel<<<N_TOKS / 256, 256, 0, stream>>>(z, A);
    vq_argmin_kernel<<<dim3(64, 8), 512, 0, stream>>>(z, emb, A, pairs);
    vq_combine_kernel<<<N_TOKS / 256, 256, 0, stream>>>(pairs, out2, fidx, counts);
    vq_gather_kernel<<<N_TOKS / 64, 256, 0, stream>>>(fidx, emb, z, out0, bsum);
    vq_final_kernel<<<1, 256, 0, stream>>>(counts, bsum, out1, out3, out4, out5);
}

// Round 9
// 419.141 us; speedup vs baseline: 2.5480x; 2.3478x over previous
//
#include <hip/hip_runtime.h>

#pragma clang fp contract(off)

#define CDIM 256
#define N_TOKS 8192
#define N_CODES 8192
#define EPS_GAP 8e-4f   // >= 2B, B = worst-case |d_tilde - d_np| (bf16 conv, CS-bounded)

typedef __bf16 bf16x8 __attribute__((ext_vector_type(8)));
typedef float f32x16 __attribute__((ext_vector_type(16)));
typedef unsigned short u16;

// ---------------- ws layout (bytes) ----------------
// 0        keys    u64[8192]      64KB   running min of enc(d~)<<32|code
// 65536    fkey    u64[8192]      64KB   exact min enc(d_np)<<32|k
// 131072   cnt     u32[8192]      32KB   candidate counts
// 163840   A       f32[8192]      32KB   numpy-pairwise ||z||^2
// 196608   counts  u32[8192]      32KB   histogram
// 229376   bsum    f32[8]         32B
// 229440   fidx    u32[8192]      32KB
// 262208   cand    u16[8192*128]  2MB
// 2359360  zperm   u16[2M]        4MB    A-fragment-ordered bf16 z
// 6553664  eperm   u16[2M]        4MB    B-fragment-ordered bf16 emb

__device__ __forceinline__ unsigned enc_f(float f) {
    unsigned u = __float_as_uint(f);
    return (u & 0x80000000u) ? ~u : (u | 0x80000000u);
}
__device__ __forceinline__ float dec_f(unsigned u) {
    u = (u & 0x80000000u) ? (u ^ 0x80000000u) : ~u;
    return __uint_as_float(u);
}
__device__ __forceinline__ u16 bf16_rne(float f) {
    const unsigned x = __float_as_uint(f);
    const unsigned r = x + 0x7FFFu + ((x >> 16) & 1u);
    return (u16)(r >> 16);
}

// ---------------- A_n = np.sum(zf*zf, axis=1), numpy pairwise order ----------
__global__ void vq_A_kernel(const float* __restrict__ z, float* __restrict__ A) {
    #pragma clang fp contract(off)
    const int n = blockIdx.x * blockDim.x + threadIdx.x;
    const int b = n >> 10, hw = n & 1023;
    const float* zp = z + (size_t)b * (CDIM * 1024) + hw;
    float halves[2];
    #pragma unroll
    for (int h = 0; h < 2; ++h) {
        const int base = h * 128;
        float r[8];
        #pragma unroll
        for (int j = 0; j < 8; ++j) {
            const float v = zp[(size_t)(base + j) * 1024];
            r[j] = v * v;
        }
        for (int i = 8; i < 128; i += 8) {
            #pragma unroll
            for (int j = 0; j < 8; ++j) {
                const float v = zp[(size_t)(base + i + j) * 1024];
                const float x = v * v;
                r[j] = r[j] + x;
            }
        }
        halves[h] = ((r[0] + r[1]) + (r[2] + r[3])) + ((r[4] + r[5]) + (r[6] + r[7]));
    }
    A[n] = halves[0] + halves[1];
}

// ---------------- build zperm: A-fragment order for 32x32x16 bf16 ------------
// idx8 = (tb*16 + kk)*64 + lane; elem i: Z[tok = tb*32 + (l&31)][c = kk*16 + (l>>5)*8 + i]
__global__ void vq_perm_z_kernel(const float* __restrict__ z, u16* __restrict__ zperm) {
    const int id = blockIdx.x * blockDim.x + threadIdx.x;   // 262144 threads
    const int l  = id & 63;
    const int kk = (id >> 6) & 15;
    const int tb = id >> 10;
    const int tok = tb * 32 + (l & 31);
    const int b = tok >> 10, hw = tok & 1023;
    const int c0 = kk * 16 + (l >> 5) * 8;
    const float* zp = z + (size_t)b * (CDIM * 1024) + hw;
    unsigned pk[4];
    #pragma unroll
    for (int h = 0; h < 4; ++h) {
        const u16 lo = bf16_rne(zp[(size_t)(c0 + 2 * h + 0) * 1024]);
        const u16 hi2 = bf16_rne(zp[(size_t)(c0 + 2 * h + 1) * 1024]);
        pk[h] = (unsigned)lo | ((unsigned)hi2 << 16);
    }
    *(uint4*)(zperm + (size_t)id * 8) = make_uint4(pk[0], pk[1], pk[2], pk[3]);
}

// ---------------- build eperm: B-fragment order -----------------------------
// idx8 = (cb*16 + kk)*64 + lane; elem i: E[code = cb*32 + (l&31)][c = kk*16 + (l>>5)*8 + i]
__global__ void vq_perm_e_kernel(const float* __restrict__ emb, u16* __restrict__ eperm) {
    const int id = blockIdx.x * blockDim.x + threadIdx.x;
    const int l  = id & 63;
    const int kk = (id >> 6) & 15;
    const int cb = id >> 10;
    const int code = cb * 32 + (l & 31);
    const int c0 = kk * 16 + (l >> 5) * 8;
    const float* ep = emb + (size_t)code * CDIM + c0;
    unsigned pk[4];
    #pragma unroll
    for (int h = 0; h < 4; ++h) {
        const u16 lo = bf16_rne(ep[2 * h + 0]);
        const u16 hi2 = bf16_rne(ep[2 * h + 1]);
        pk[h] = (unsigned)lo | ((unsigned)hi2 << 16);
    }
    *(uint4*)(eperm + (size_t)id * 8) = make_uint4(pk[0], pk[1], pk[2], pk[3]);
}

// ---------------- MFMA approx pass: min-track + candidate collect -----------
// grid (256, 16), 256 thr = 4 waves. Wave: 32 tok x 128 codes (4 x 32x32 tiles),
// K=256 = 16 ksteps of 32x32x16 MFMA. A/B frags direct from pre-permuted global.
// D layout (m74/m101): col = lane&31, row = (reg&3) + 8*(reg>>2) + 4*(lane>>5).
__global__ __launch_bounds__(256) void vq_mfma_kernel(
        const u16* __restrict__ zperm, const u16* __restrict__ eperm,
        const float* __restrict__ A, unsigned long long* __restrict__ keys,
        unsigned* __restrict__ cnt, u16* __restrict__ cand) {
    const int t = threadIdx.x;
    const int w = t >> 6;
    const int l = t & 63;
    const int hi = l >> 5;
    const int col = l & 31;
    const int tb = blockIdx.x;
    const int tok0 = tb * 32;
    const int cbs0 = blockIdx.y * 16 + w * 4;   // first of 4 code-blocks (32 codes each)

    f32x16 a0 = {}, a1 = {}, a2 = {}, a3 = {};

    #pragma unroll
    for (int kk = 0; kk < 16; ++kk) {
        const uint4 av = *(const uint4*)(zperm + ((size_t)(tb * 16 + kk) * 64 + l) * 8);
        const uint4 bv0 = *(const uint4*)(eperm + ((size_t)((cbs0 + 0) * 16 + kk) * 64 + l) * 8);
        const uint4 bv1 = *(const uint4*)(eperm + ((size_t)((cbs0 + 1) * 16 + kk) * 64 + l) * 8);
        const uint4 bv2 = *(const uint4*)(eperm + ((size_t)((cbs0 + 2) * 16 + kk) * 64 + l) * 8);
        const uint4 bv3 = *(const uint4*)(eperm + ((size_t)((cbs0 + 3) * 16 + kk) * 64 + l) * 8);
        const bf16x8 af = __builtin_bit_cast(bf16x8, av);
        a0 = __builtin_amdgcn_mfma_f32_32x32x16_bf16(af, __builtin_bit_cast(bf16x8, bv0), a0, 0, 0, 0);
        a1 = __builtin_amdgcn_mfma_f32_32x32x16_bf16(af, __builtin_bit_cast(bf16x8, bv1), a1, 0, 0, 0);
        a2 = __builtin_amdgcn_mfma_f32_32x32x16_bf16(af, __builtin_bit_cast(bf16x8, bv2), a2, 0, 0, 0);
        a3 = __builtin_amdgcn_mfma_f32_32x32x16_bf16(af, __builtin_bit_cast(bf16x8, bv3), a3, 0, 0, 0);
    }

    // ---- fold: d~ = A - 2*acc; per-row min over this wave's 128 codes ----
    float Arow[16];
    #pragma unroll
    for (int r = 0; r < 16; ++r) {
        const int row = (r & 3) + 8 * (r >> 2) + 4 * hi;
        Arow[r] = A[tok0 + row];
    }
    unsigned long long bestk[16];
    #pragma unroll
    for (int r = 0; r < 16; ++r) {
        unsigned long long m = ~0ull;
        unsigned long long k;
        k = ((unsigned long long)enc_f(Arow[r] - 2.0f * a0[r]) << 32) | (unsigned)((cbs0 + 0) * 32 + col);
        m = k < m ? k : m;
        k = ((unsigned long long)enc_f(Arow[r] - 2.0f * a1[r]) << 32) | (unsigned)((cbs0 + 1) * 32 + col);
        m = k < m ? k : m;
        k = ((unsigned long long)enc_f(Arow[r] - 2.0f * a2[r]) << 32) | (unsigned)((cbs0 + 2) * 32 + col);
        m = k < m ? k : m;
        k = ((unsigned long long)enc_f(Arow[r] - 2.0f * a3[r]) << 32) | (unsigned)((cbs0 + 3) * 32 + col);
        m = k < m ? k : m;
        bestk[r] = m;
    }
    // cross-lane min within each 32-lane group
    #pragma unroll
    for (int off = 1; off < 32; off <<= 1) {
        #pragma unroll
        for (int r = 0; r < 16; ++r) {
            const unsigned long long o =
                (unsigned long long)__shfl_xor((long long)bestk[r], off, 64);
            bestk[r] = o < bestk[r] ? o : bestk[r];
        }
    }
    // lane 0 of each group: global atomicMin; broadcast running global min
    unsigned long long g[16];
    #pragma unroll
    for (int r = 0; r < 16; ++r) {
        const int row = (r & 3) + 8 * (r >> 2) + 4 * hi;
        unsigned long long gm = 0;
        if (col == 0) {
            const unsigned long long ret = atomicMin(&keys[tok0 + row], bestk[r]);
            gm = ret < bestk[r] ? ret : bestk[r];
        }
        g[r] = (unsigned long long)__shfl((long long)gm, hi * 32, 64);
    }
    // candidate emit: enc(d~) <= enc(dec(gmin) + EPS)
    #pragma unroll
    for (int r = 0; r < 16; ++r) {
        const int row = (r & 3) + 8 * (r >> 2) + 4 * hi;
        const int tokr = tok0 + row;
        const unsigned thrE = enc_f(dec_f((unsigned)(g[r] >> 32)) + EPS_GAP);
        float d; unsigned e;
        d = Arow[r] - 2.0f * a0[r]; e = enc_f(d);
        if (e <= thrE) { const unsigned pos = atomicAdd(&cnt[tokr], 1u);
            if (pos < 127u) cand[(size_t)tokr * 128 + pos] = (u16)((cbs0 + 0) * 32 + col); }
        d = Arow[r] - 2.0f * a1[r]; e = enc_f(d);
        if (e <= thrE) { const unsigned pos = atomicAdd(&cnt[tokr], 1u);
            if (pos < 127u) cand[(size_t)tokr * 128 + pos] = (u16)((cbs0 + 1) * 32 + col); }
        d = Arow[r] - 2.0f * a2[r]; e = enc_f(d);
        if (e <= thrE) { const unsigned pos = atomicAdd(&cnt[tokr], 1u);
            if (pos < 127u) cand[(size_t)tokr * 128 + pos] = (u16)((cbs0 + 2) * 32 + col); }
        d = Arow[r] - 2.0f * a3[r]; e = enc_f(d);
        if (e <= thrE) { const unsigned pos = atomicAdd(&cnt[tokr], 1u);
            if (pos < 127u) cand[(size_t)tokr * 128 + pos] = (u16)((cbs0 + 3) * 32 + col); }
    }
}

// ---------------- exact numpy-order distance for one (token,code) -----------
__device__ __forceinline__ unsigned long long vq_exact_key(
        const float* zr, const float* __restrict__ emb, float An, int k) {
    #pragma clang fp contract(off)
    const float* er = emb + (size_t)k * CDIM;
    float l0 = 0.0f, l1 = 0.0f, l2 = 0.0f, l3 = 0.0f;
    #pragma unroll 8
    for (int m = 0; m < 64; ++m) {
        const float4 ev = *(const float4*)(er + m * 4);
        const float4 zv = *(const float4*)(zr + m * 4);
        float p;
        p = zv.x * ev.x; l0 = l0 + p;   // rne product, rne add (no FMA)
        p = zv.y * ev.y; l1 = l1 + p;
        p = zv.z * ev.z; l2 = l2 + p;
        p = zv.w * ev.w; l3 = l3 + p;
    }
    const float gsum = (l0 + l1) + (l2 + l3);
    const float d = An - 2.0f * gsum;
    return ((unsigned long long)enc_f(d) << 32) | (unsigned)k;
}

// ---------------- exact pass: candidates (or full-scan fallback) ------------
__global__ __launch_bounds__(256) void vq_exact_kernel(
        const float* __restrict__ z, const float* __restrict__ emb,
        const float* __restrict__ A, const unsigned* __restrict__ cnt,
        const u16* __restrict__ cand, unsigned long long* __restrict__ fkey) {
    #pragma clang fp contract(off)
    __shared__ float zrow[4][256];
    const int t = threadIdx.x, w = t >> 6, l = t & 63;
    const int n = blockIdx.x * 4 + w;
    const int b = n >> 10, hw = n & 1023;
    #pragma unroll
    for (int q = 0; q < 4; ++q)
        zrow[w][l + 64 * q] = z[(size_t)b * (CDIM * 1024) + (size_t)(l + 64 * q) * 1024 + hw];
    __syncthreads();
    const float An = A[n];
    const unsigned c = cnt[n];
    if (c - 1u < 127u) {            // 1..127 candidates: exact on each
        for (unsigned p = l; p < c; p += 64) {
            const int k = cand[(size_t)n * 128 + p];
            const unsigned long long key = vq_exact_key(&zrow[w][0], emb, An, k);
            atomicMin(&fkey[n], key);
        }
    } else {                         // 0 or overflow: full exact scan (always correct)
        unsigned long long m = ~0ull;
        for (int k = l; k < N_CODES; k += 64) {
            const unsigned long long key = vq_exact_key(&zrow[w][0], emb, An, k);
            m = key < m ? key : m;
        }
        atomicMin(&fkey[n], m);
    }
}

// ---------------- decode fkey -> fidx, out2, histogram ----------------
__global__ void vq_decode_kernel(const unsigned long long* __restrict__ fkey,
                                 float* __restrict__ out2, unsigned* __restrict__ fidx,
                                 unsigned* __restrict__ counts) {
    const int n = blockIdx.x * blockDim.x + threadIdx.x;
    const unsigned idx = (unsigned)(fkey[n] & 0xFFFFFFFFull);
    fidx[n] = idx;
    out2[n] = (float)idx;
    atomicAdd(&counts[idx], 1u);
}

// ---------------- gather z_q, ST-exact out0, per-batch MSE ----------------
__global__ void vq_gather_kernel(const unsigned* __restrict__ fidx,
                                 const float* __restrict__ emb,
                                 const float* __restrict__ z,
                                 float* __restrict__ out0, float* __restrict__ bsum) {
    #pragma clang fp contract(off)
    __shared__ float tile[64][257];
    const int t    = threadIdx.x;
    const int tok0 = blockIdx.x * 64;
    const int b    = tok0 >> 10;
    const int hw0  = tok0 & 1023;

    const int tt = t >> 2;
    const int q  = t & 3;
    const int idx = (int)fidx[tok0 + tt];
    const float* er = emb + (size_t)idx * CDIM;
    #pragma unroll
    for (int i = 0; i < 16; ++i) {
        const int f = i * 4 + q;
        float4 v = *(const float4*)(er + f * 4);
        tile[tt][f * 4 + 0] = v.x;
        tile[tt][f * 4 + 1] = v.y;
        tile[tt][f * 4 + 2] = v.z;
        tile[tt][f * 4 + 3] = v.w;
    }
    __syncthreads();

    const int jj = t & 63;
    const int c0 = t >> 6;
    const size_t base = (size_t)b * (CDIM * 1024) + hw0 + jj;
    float s = 0.0f;
    #pragma unroll 4
    for (int c = c0; c < CDIM; c += 4) {
        const float v  = tile[jj][c];
        const float zv = z[base + (size_t)c * 1024];
        const float d  = v - zv;                  // fl(z_q - z)
        out0[base + (size_t)c * 1024] = zv + d;   // straight-through
        s += d * d;
    }
    #pragma unroll
    for (int o = 32; o > 0; o >>= 1) s += __shfl_down(s, o, 64);
    __shared__ float w4[4];
    if ((t & 63) == 0) w4[t >> 6] = s;
    __syncthreads();
    if (t == 0) atomicAdd(&bsum[b], w4[0] + w4[1] + w4[2] + w4[3]);
}

// ---------------- finalize ----------------
__global__ void vq_final_kernel(const unsigned* __restrict__ counts,
                                const float* __restrict__ bsum,
                                float* __restrict__ out1, float* __restrict__ out3,
                                float* __restrict__ out4, float* __restrict__ out5) {
    const int t = threadIdx.x;
    float s = 0.0f;
    for (int k = t; k < N_CODES; k += 256) {
        const float p = (float)counts[k] * (1.0f / 8192.0f);
        s += p * logf(p + 1e-10f);
    }
    #pragma unroll
    for (int o = 32; o > 0; o >>= 1) s += __shfl_down(s, o, 64);
    __shared__ float w4[4];
    if ((t & 63) == 0) w4[t >> 6] = s;
    __syncthreads();
    if (t == 0) {
        out5[0] = expf(-(w4[0] + w4[1] + w4[2] + w4[3]));
        float tot = 0.0f;
        #pragma unroll
        for (int b = 0; b < 8; ++b) {
            const float m = bsum[b] * (1.0f / 262144.0f);
            out1[b] = 1.25f * m;
            tot += m;
        }
        const float mean_mse = tot * 0.125f;
        out3[0] = mean_mse;
        out4[0] = 0.25f * mean_mse;
    }
}

extern "C" void kernel_launch(void* const* d_in, const int* in_sizes, int n_in,
                              void* d_out, int out_size, void* d_ws, size_t ws_size,
                              hipStream_t stream) {
    const float* z   = (const float*)d_in[0];
    const float* emb = (const float*)d_in[1];
    float* out = (float*)d_out;

    float* out0 = out;                 // z_q_st (NCHW), 2097152
    float* out1 = out + 2097152;       // loss [8]
    float* out2 = out + 2097160;       // idx as float [8192]
    float* out3 = out + 2105352;       // mean commit
    float* out4 = out + 2105353;       // beta * mean emb
    float* out5 = out + 2105354;       // perplexity

    char* ws = (char*)d_ws;
    unsigned long long* keys = (unsigned long long*)(ws + 0);
    unsigned long long* fkey = (unsigned long long*)(ws + 65536);
    unsigned* cnt    = (unsigned*)(ws + 131072);
    float*    A      = (float*)(ws + 163840);
    unsigned* counts = (unsigned*)(ws + 196608);
    float*    bsum   = (float*)(ws + 229376);
    unsigned* fidx   = (unsigned*)(ws + 229440);
    u16*      cand   = (u16*)(ws + 262208);
    u16*      zperm  = (u16*)(ws + 2359360);
    u16*      eperm  = (u16*)(ws + 6553664);

    hipMemsetAsync(ws, 0xFF, 131072, stream);              // keys + fkey
    hipMemsetAsync(ws + 131072, 0, 32768, stream);         // cnt
    hipMemsetAsync(ws + 196608, 0, 32768 + 64, stream);    // counts + bsum

    vq_A_kernel<<<N_TOKS / 256, 256, 0, stream>>>(z, A);
    vq_perm_z_kernel<<<1024, 256, 0, stream>>>(z, zperm);
    vq_perm_e_kernel<<<1024, 256, 0, stream>>>(emb, eperm);
    vq_mfma_kernel<<<dim3(256, 16), 256, 0, stream>>>(zperm, eperm, A, keys, cnt, cand);
    vq_exact_kernel<<<N_TOKS / 4, 256, 0, stream>>>(z, emb, A, cnt, cand, fkey);
    vq_decode_kernel<<<N_TOKS / 256, 256, 0, stream>>>(fkey, out2, fidx, counts);
    vq_gather_kernel<<<N_TOKS / 64, 256, 0, stream>>>(fidx, emb, z, out0, bsum);
    vq_final_kernel<<<1, 256, 0, stream>>>(counts, bsum, out1, out3, out4, out5);
}